// Round 5
// baseline (379.686 us; speedup 1.0000x reference)
//
#include <hip/hip_runtime.h>

#define NLVL 16
#define LOGT 19
#define TMASK ((1u << LOGT) - 1u)
#define SCALE 4096.0f
#define INV_SCALE (1.0f / 4096.0f)

typedef _Float16 half_t;
typedef half_t half8 __attribute__((ext_vector_type(8)));
typedef half_t half4 __attribute__((ext_vector_type(4)));
typedef half_t half2v __attribute__((ext_vector_type(2)));
typedef float  float4v __attribute__((ext_vector_type(4)));

__device__ __constant__ float RES_C[NLVL] = {16.f, 20.f, 25.f, 32.f, 40.f, 50.f, 64.f, 80.f,
                                             101.f, 128.f, 161.f, 203.f, 256.f, 322.f, 406.f, 512.f};

__device__ __forceinline__ float4v mfma16(half8 a, half8 b, float4v c) {
    return __builtin_amdgcn_mfma_f32_16x16x32_f16(a, b, c, 0, 0, 0);
}

// ---------------- Kernel A: hash-grid encode, one thread per (point, level) ----------------
__global__ __launch_bounds__(256, 8) void nerf_encode(
    const float* __restrict__ coords,
    const float2* __restrict__ tab,
    half_t* __restrict__ encOut, int npts)
{
    const int t = blockIdx.x * 256 + threadIdx.x;
    const int p = t >> 4;
    const int l = t & 15;

    const float cx = coords[p * 3 + 0];
    const float cy = coords[p * 3 + 1];
    const float cz = coords[p * 3 + 2];

    const float r = RES_C[l];
    const float sx = cx * r, sy = cy * r, sz = cz * r;
    const float fx = floorf(sx), fy = floorf(sy), fz = floorf(sz);
    const float gx = ceilf(sx),  gy = ceilf(sy),  gz = ceilf(sz);

    const unsigned hfx = (unsigned)(int)fx;
    const unsigned hgx = (unsigned)(int)gx;
    const unsigned hfy = (unsigned)(int)fy * 2654435761u;
    const unsigned hgy = (unsigned)(int)gy * 2654435761u;
    const unsigned hfz = (unsigned)(int)fz * 805459861u;
    const unsigned hgz = (unsigned)(int)gz * 805459861u;

    const float tx = sx - fx, ty = sy - fy, tz = sz - fz;
    const float ux = gx - sx, uy = gy - sy, uz = gz - sz;

    const float2* __restrict__ base = tab + (((unsigned)l) << LOGT);

    // issue all 8 gathers as one independent batch (max outstanding loads)
    float2 fv[8];
    float  w[8];
    #pragma unroll
    for (int o = 0; o < 8; ++o) {
        const unsigned h = ((o & 4) ? hgx : hfx)
                         ^ ((o & 2) ? hgy : hfy)
                         ^ ((o & 1) ? hgz : hfz);
        w[o] = (((o & 4) ? tx : ux) * ((o & 2) ? ty : uy)) * ((o & 1) ? tz : uz);
        fv[o] = base[h & TMASK];
    }
    float e0 = 0.f, e1 = 0.f;
    #pragma unroll
    for (int o = 0; o < 8; ++o) {
        e0 = fmaf(w[o], fv[o].x, e0);
        e1 = fmaf(w[o], fv[o].y, e1);
    }

    half2v hv;
    hv[0] = (half_t)(e0 * SCALE);
    hv[1] = (half_t)(e1 * SCALE);
    *reinterpret_cast<half2v*>(&encOut[(size_t)p * 32 + l * 2]) = hv;
}

// ---------------- Kernel B: MFMA MLP (R4 structure, enc from global) ----------------
__global__ __launch_bounds__(256, 2) void nerf_mlp(
    const half_t* __restrict__ encG,
    const float* __restrict__ w_in, const float* __restrict__ b_in,
    const float* __restrict__ w_h0, const float* __restrict__ b_h0,
    const float* __restrict__ w_h1, const float* __restrict__ b_h1,
    const float* __restrict__ w_out, const float* __restrict__ b_out,
    float* __restrict__ out, int npts)
{
    __shared__ half_t actS[4][2][32 * 64];

    const int t    = threadIdx.x;
    const int lane = t & 63;
    const int wv   = t >> 6;
    const int m    = lane & 15;
    const int quad = lane >> 4;

    // A-frag layout: A[m = lane&15][k = quad*8 + j]
    auto loadA = [&](const float* __restrict__ W, int ncol, int row, int col) -> half8 {
        const float* p = W + row * ncol + col;
        const float4v lo = *reinterpret_cast<const float4v*>(p);
        const float4v hi = *reinterpret_cast<const float4v*>(p + 4);
        half8 r;
        r[0] = (half_t)lo[0]; r[1] = (half_t)lo[1]; r[2] = (half_t)lo[2]; r[3] = (half_t)lo[3];
        r[4] = (half_t)hi[0]; r[5] = (half_t)hi[1]; r[6] = (half_t)hi[2]; r[7] = (half_t)hi[3];
        return r;
    };

    half8 aL1[4], aL2[8], aL3[8], aL4[2];
    #pragma unroll
    for (int mt = 0; mt < 4; ++mt) aL1[mt] = loadA(w_in, 32, mt * 16 + m, quad * 8);
    #pragma unroll
    for (int mt = 0; mt < 4; ++mt) {
        aL2[mt * 2 + 0] = loadA(w_h0, 64, mt * 16 + m, 0 * 32 + quad * 8);
        aL2[mt * 2 + 1] = loadA(w_h0, 64, mt * 16 + m, 1 * 32 + quad * 8);
        aL3[mt * 2 + 0] = loadA(w_h1, 64, mt * 16 + m, 0 * 32 + quad * 8);
        aL3[mt * 2 + 1] = loadA(w_h1, 64, mt * 16 + m, 1 * 32 + quad * 8);
    }
    aL4[0] = loadA(w_out, 64, m, 0 * 32 + quad * 8);
    aL4[1] = loadA(w_out, 64, m, 1 * 32 + quad * 8);

    float4v bL1[4], bL2[4], bL3[4], bL4;
    #pragma unroll
    for (int mt = 0; mt < 4; ++mt) {
        bL1[mt] = *reinterpret_cast<const float4v*>(b_in + mt * 16 + quad * 4);
        bL2[mt] = *reinterpret_cast<const float4v*>(b_h0 + mt * 16 + quad * 4);
        bL3[mt] = *reinterpret_cast<const float4v*>(b_h1 + mt * 16 + quad * 4);
    }
    bL4 = *reinterpret_cast<const float4v*>(b_out + quad * 4);

    half_t* const ping = &actS[wv][0][0];
    half_t* const pong = &actS[wv][1][0];
    const float4v zero = {0.f, 0.f, 0.f, 0.f};

    auto storeTile = [&](half_t* buf, int lp, int mt, float4v acc, float4v bias) {
        half4 h4;
        #pragma unroll
        for (int r = 0; r < 4; ++r)
            h4[r] = (half_t)fmaxf(fmaf(bias[r], SCALE, acc[r]), 0.f);
        const int c16  = mt * 2 + (quad >> 1);
        const int phys = c16 ^ (lp & 7);
        *reinterpret_cast<half4*>(&buf[lp * 64 + phys * 8 + (quad & 1) * 4]) = h4;
    };
    auto loadB = [&](const half_t* buf, int lp, int h) -> half8 {
        const int phys = (h * 4 + quad) ^ (lp & 7);
        return *reinterpret_cast<const half8*>(&buf[lp * 64 + phys * 8]);
    };

    for (int g = 0; g < 2; ++g) {
        #pragma unroll
        for (int nt = 0; nt < 2; ++nt) {
            const int lp  = nt * 16 + m;
            const size_t ptg = (size_t)blockIdx.x * 256 + (size_t)wv * 64 + g * 32 + lp;

            // ---- layer 1: enc(32) -> h0(64), B-frag straight from global ----
            const half8 be = *reinterpret_cast<const half8*>(&encG[ptg * 32 + quad * 8]);
            #pragma unroll
            for (int mt = 0; mt < 4; ++mt) {
                float4v acc = mfma16(aL1[mt], be, zero);
                storeTile(ping, lp, mt, acc, bL1[mt]);
            }

            // ---- layer 2 ----
            {
                const half8 p0 = loadB(ping, lp, 0);
                const half8 p1 = loadB(ping, lp, 1);
                #pragma unroll
                for (int mt = 0; mt < 4; ++mt) {
                    float4v acc = mfma16(aL2[mt * 2 + 0], p0, zero);
                    acc         = mfma16(aL2[mt * 2 + 1], p1, acc);
                    storeTile(pong, lp, mt, acc, bL2[mt]);
                }
            }

            // ---- layer 3 ----
            {
                const half8 p0 = loadB(pong, lp, 0);
                const half8 p1 = loadB(pong, lp, 1);
                #pragma unroll
                for (int mt = 0; mt < 4; ++mt) {
                    float4v acc = mfma16(aL3[mt * 2 + 0], p0, zero);
                    acc         = mfma16(aL3[mt * 2 + 1], p1, acc);
                    storeTile(ping, lp, mt, acc, bL3[mt]);
                }
            }

            // ---- layer 4 ----
            {
                const half8 p0 = loadB(ping, lp, 0);
                const half8 p1 = loadB(ping, lp, 1);
                float4v acc = mfma16(aL4[0], p0, zero);
                acc         = mfma16(aL4[1], p1, acc);
                float4v res;
                #pragma unroll
                for (int r = 0; r < 4; ++r)
                    res[r] = fmaf(acc[r], INV_SCALE, bL4[r]);
                *reinterpret_cast<float4v*>(out + ptg * 16 + quad * 4) = res;
            }
        }
    }
}

// ---------------- Fallback: R4 fused kernel (used only if ws too small) ----------------
__global__ __launch_bounds__(256, 2) void nerf_fused(
    const float* __restrict__ coords,
    const float2* __restrict__ tab,
    const float* __restrict__ w_in, const float* __restrict__ b_in,
    const float* __restrict__ w_h0, const float* __restrict__ b_h0,
    const float* __restrict__ w_h1, const float* __restrict__ b_h1,
    const float* __restrict__ w_out, const float* __restrict__ b_out,
    float* __restrict__ out, int npts)
{
    __shared__ half_t encS[256 * 40];
    __shared__ half_t actS[4][2][32 * 64];

    const int t    = threadIdx.x;
    const int lane = t & 63;
    const int wv   = t >> 6;
    const int m    = lane & 15;
    const int quad = lane >> 4;
    const int pt = blockIdx.x * 256 + t;

    {
        const float cx = coords[pt * 3 + 0];
        const float cy = coords[pt * 3 + 1];
        const float cz = coords[pt * 3 + 2];
        float enc[32];
        #pragma unroll
        for (int l = 0; l < NLVL; ++l) {
            const float r = RES_C[l];
            const float sx = cx * r, sy = cy * r, sz = cz * r;
            const float fx = floorf(sx), fy = floorf(sy), fz = floorf(sz);
            const float gx = ceilf(sx),  gy = ceilf(sy),  gz = ceilf(sz);
            const unsigned hfx = (unsigned)(int)fx;
            const unsigned hgx = (unsigned)(int)gx;
            const unsigned hfy = (unsigned)(int)fy * 2654435761u;
            const unsigned hgy = (unsigned)(int)gy * 2654435761u;
            const unsigned hfz = (unsigned)(int)fz * 805459861u;
            const unsigned hgz = (unsigned)(int)gz * 805459861u;
            const float tx = sx - fx, ty = sy - fy, tz = sz - fz;
            const float ux = gx - sx, uy = gy - sy, uz = gz - sz;
            const unsigned lbase = ((unsigned)l) << LOGT;
            float e0 = 0.f, e1 = 0.f;
            #pragma unroll
            for (int o = 0; o < 8; ++o) {
                const unsigned h = ((o & 4) ? hgx : hfx)
                                 ^ ((o & 2) ? hgy : hfy)
                                 ^ ((o & 1) ? hgz : hfz);
                const unsigned idx = h & TMASK;
                const float w = (((o & 4) ? tx : ux)
                              *  ((o & 2) ? ty : uy))
                              *  ((o & 1) ? tz : uz);
                const float2 fv = tab[lbase + idx];
                e0 = fmaf(w, fv.x, e0);
                e1 = fmaf(w, fv.y, e1);
            }
            enc[2 * l + 0] = e0;
            enc[2 * l + 1] = e1;
        }
        #pragma unroll
        for (int c = 0; c < 4; ++c) {
            half8 h8;
            #pragma unroll
            for (int j = 0; j < 8; ++j) h8[j] = (half_t)(enc[c * 8 + j] * SCALE);
            *reinterpret_cast<half8*>(&encS[t * 40 + c * 8]) = h8;
        }
    }

    auto loadA = [&](const float* __restrict__ W, int ncol, int row, int col) -> half8 {
        const float* p = W + row * ncol + col;
        const float4v lo = *reinterpret_cast<const float4v*>(p);
        const float4v hi = *reinterpret_cast<const float4v*>(p + 4);
        half8 r;
        r[0] = (half_t)lo[0]; r[1] = (half_t)lo[1]; r[2] = (half_t)lo[2]; r[3] = (half_t)lo[3];
        r[4] = (half_t)hi[0]; r[5] = (half_t)hi[1]; r[6] = (half_t)hi[2]; r[7] = (half_t)hi[3];
        return r;
    };

    half8 aL1[4], aL2[8], aL3[8], aL4[2];
    #pragma unroll
    for (int mt = 0; mt < 4; ++mt) aL1[mt] = loadA(w_in, 32, mt * 16 + m, quad * 8);
    #pragma unroll
    for (int mt = 0; mt < 4; ++mt) {
        aL2[mt * 2 + 0] = loadA(w_h0, 64, mt * 16 + m, 0 * 32 + quad * 8);
        aL2[mt * 2 + 1] = loadA(w_h0, 64, mt * 16 + m, 1 * 32 + quad * 8);
        aL3[mt * 2 + 0] = loadA(w_h1, 64, mt * 16 + m, 0 * 32 + quad * 8);
        aL3[mt * 2 + 1] = loadA(w_h1, 64, mt * 16 + m, 1 * 32 + quad * 8);
    }
    aL4[0] = loadA(w_out, 64, m, 0 * 32 + quad * 8);
    aL4[1] = loadA(w_out, 64, m, 1 * 32 + quad * 8);

    float4v bL1[4], bL2[4], bL3[4], bL4;
    #pragma unroll
    for (int mt = 0; mt < 4; ++mt) {
        bL1[mt] = *reinterpret_cast<const float4v*>(b_in + mt * 16 + quad * 4);
        bL2[mt] = *reinterpret_cast<const float4v*>(b_h0 + mt * 16 + quad * 4);
        bL3[mt] = *reinterpret_cast<const float4v*>(b_h1 + mt * 16 + quad * 4);
    }
    bL4 = *reinterpret_cast<const float4v*>(b_out + quad * 4);

    half_t* const ping = &actS[wv][0][0];
    half_t* const pong = &actS[wv][1][0];
    const float4v zero = {0.f, 0.f, 0.f, 0.f};

    auto storeTile = [&](half_t* buf, int lp, int mt, float4v acc, float4v bias) {
        half4 h4;
        #pragma unroll
        for (int r = 0; r < 4; ++r)
            h4[r] = (half_t)fmaxf(fmaf(bias[r], SCALE, acc[r]), 0.f);
        const int c16  = mt * 2 + (quad >> 1);
        const int phys = c16 ^ (lp & 7);
        *reinterpret_cast<half4*>(&buf[lp * 64 + phys * 8 + (quad & 1) * 4]) = h4;
    };
    auto loadB = [&](const half_t* buf, int lp, int h) -> half8 {
        const int phys = (h * 4 + quad) ^ (lp & 7);
        return *reinterpret_cast<const half8*>(&buf[lp * 64 + phys * 8]);
    };

    for (int g = 0; g < 2; ++g) {
        #pragma unroll
        for (int nt = 0; nt < 2; ++nt) {
            const int lp   = nt * 16 + m;
            const int prow = wv * 64 + g * 32 + lp;
            const half8 be = *reinterpret_cast<const half8*>(&encS[prow * 40 + quad * 8]);
            #pragma unroll
            for (int mt = 0; mt < 4; ++mt) {
                float4v acc = mfma16(aL1[mt], be, zero);
                storeTile(ping, lp, mt, acc, bL1[mt]);
            }
            {
                const half8 p0 = loadB(ping, lp, 0);
                const half8 p1 = loadB(ping, lp, 1);
                #pragma unroll
                for (int mt = 0; mt < 4; ++mt) {
                    float4v acc = mfma16(aL2[mt * 2 + 0], p0, zero);
                    acc         = mfma16(aL2[mt * 2 + 1], p1, acc);
                    storeTile(pong, lp, mt, acc, bL2[mt]);
                }
            }
            {
                const half8 p0 = loadB(pong, lp, 0);
                const half8 p1 = loadB(pong, lp, 1);
                #pragma unroll
                for (int mt = 0; mt < 4; ++mt) {
                    float4v acc = mfma16(aL3[mt * 2 + 0], p0, zero);
                    acc         = mfma16(aL3[mt * 2 + 1], p1, acc);
                    storeTile(ping, lp, mt, acc, bL3[mt]);
                }
            }
            {
                const half8 p0 = loadB(ping, lp, 0);
                const half8 p1 = loadB(ping, lp, 1);
                float4v acc = mfma16(aL4[0], p0, zero);
                acc         = mfma16(aL4[1], p1, acc);
                float4v res;
                #pragma unroll
                for (int r = 0; r < 4; ++r)
                    res[r] = fmaf(acc[r], INV_SCALE, bL4[r]);
                const size_t ptg = (size_t)blockIdx.x * 256 + (size_t)wv * 64 + g * 32 + lp;
                *reinterpret_cast<float4v*>(out + ptg * 16 + quad * 4) = res;
            }
        }
    }
}

extern "C" void kernel_launch(void* const* d_in, const int* in_sizes, int n_in,
                              void* d_out, int out_size, void* d_ws, size_t ws_size,
                              hipStream_t stream) {
    const float*  coords = (const float*)d_in[0];
    const float2* tables = (const float2*)d_in[1];
    const float*  w_in   = (const float*)d_in[2];
    const float*  b_in   = (const float*)d_in[3];
    const float*  w_h0   = (const float*)d_in[4];
    const float*  b_h0   = (const float*)d_in[5];
    const float*  w_h1   = (const float*)d_in[6];
    const float*  b_h1   = (const float*)d_in[7];
    const float*  w_out  = (const float*)d_in[8];
    const float*  b_out  = (const float*)d_in[9];
    float* out = (float*)d_out;

    const int npts = in_sizes[0] / 3;      // 262144
    const size_t encBytes = (size_t)npts * 32 * sizeof(half_t);  // 16.8 MB

    if (ws_size >= encBytes) {
        half_t* encG = (half_t*)d_ws;
        const int gridA = (npts * 16) / 256;
        nerf_encode<<<gridA, 256, 0, stream>>>(coords, tables, encG, npts);
        const int gridB = npts / 256;
        nerf_mlp<<<gridB, 256, 0, stream>>>(encG,
                                            w_in, b_in, w_h0, b_h0,
                                            w_h1, b_h1, w_out, b_out,
                                            out, npts);
    } else {
        const int grid = npts / 256;
        nerf_fused<<<grid, 256, 0, stream>>>(coords, tables,
                                             w_in, b_in, w_h0, b_h0,
                                             w_h1, b_h1, w_out, b_out,
                                             out, npts);
    }
}

// Round 6
// 261.222 us; speedup vs baseline: 1.4535x; 1.4535x over previous
//
#include <hip/hip_runtime.h>

#define NLVL 16
#define LOGT 19
#define TMASK ((1u << LOGT) - 1u)
#define SCALE 4096.0f
#define INV_SCALE (1.0f / 4096.0f)

typedef _Float16 half_t;
typedef half_t half8 __attribute__((ext_vector_type(8)));
typedef half_t half4 __attribute__((ext_vector_type(4)));
typedef half_t half2v __attribute__((ext_vector_type(2)));
typedef float  float4v __attribute__((ext_vector_type(4)));

__device__ __constant__ float RES_C[NLVL] = {16.f, 20.f, 25.f, 32.f, 40.f, 50.f, 64.f, 80.f,
                                             101.f, 128.f, 161.f, 203.f, 256.f, 322.f, 406.f, 512.f};

__device__ __forceinline__ float4v mfma16(half8 a, half8 b, float4v c) {
    return __builtin_amdgcn_mfma_f32_16x16x32_f16(a, b, c, 0, 0, 0);
}

// ---------------- Kernel A: level-major encode ----------------
// Block = 256 points x ONE level. Level is the slow grid dimension, so at any
// instant only ~1-2 levels are chip-active and each XCD's 4 MB L2 holds the
// current level's table. Output transposed: encT[level][point][2] (half).
__global__ __launch_bounds__(256, 8) void nerf_encode_lvl(
    const float* __restrict__ coords,
    const float2* __restrict__ tab,
    half_t* __restrict__ encT, int npts)
{
    const int bpl = npts >> 8;                    // blocks per level
    const int l   = blockIdx.x / bpl;
    const int p   = (blockIdx.x % bpl) * 256 + threadIdx.x;

    const float cx = coords[p * 3 + 0];
    const float cy = coords[p * 3 + 1];
    const float cz = coords[p * 3 + 2];

    const float r = RES_C[l];
    const float sx = cx * r, sy = cy * r, sz = cz * r;
    const float fx = floorf(sx), fy = floorf(sy), fz = floorf(sz);
    const float gx = ceilf(sx),  gy = ceilf(sy),  gz = ceilf(sz);

    const unsigned hfx = (unsigned)(int)fx;
    const unsigned hgx = (unsigned)(int)gx;
    const unsigned hfy = (unsigned)(int)fy * 2654435761u;
    const unsigned hgy = (unsigned)(int)gy * 2654435761u;
    const unsigned hfz = (unsigned)(int)fz * 805459861u;
    const unsigned hgz = (unsigned)(int)gz * 805459861u;

    const float tx = sx - fx, ty = sy - fy, tz = sz - fz;
    const float ux = gx - sx, uy = gy - sy, uz = gz - sz;

    const float2* __restrict__ base = tab + (((unsigned)l) << LOGT);

    float2 fv[8];
    float  w[8];
    #pragma unroll
    for (int o = 0; o < 8; ++o) {
        const unsigned h = ((o & 4) ? hgx : hfx)
                         ^ ((o & 2) ? hgy : hfy)
                         ^ ((o & 1) ? hgz : hfz);
        w[o] = (((o & 4) ? tx : ux) * ((o & 2) ? ty : uy)) * ((o & 1) ? tz : uz);
        fv[o] = base[h & TMASK];
    }
    float e0 = 0.f, e1 = 0.f;
    #pragma unroll
    for (int o = 0; o < 8; ++o) {
        e0 = fmaf(w[o], fv[o].x, e0);
        e1 = fmaf(w[o], fv[o].y, e1);
    }

    half2v hv;
    hv[0] = (half_t)(e0 * SCALE);
    hv[1] = (half_t)(e1 * SCALE);
    *reinterpret_cast<half2v*>(&encT[((size_t)l * npts + p) * 2]) = hv;
}

// ---------------- Kernel B: MFMA MLP (enc from transposed global buffer) ----------------
__global__ __launch_bounds__(256, 2) void nerf_mlp(
    const half_t* __restrict__ encT,
    const float* __restrict__ w_in, const float* __restrict__ b_in,
    const float* __restrict__ w_h0, const float* __restrict__ b_h0,
    const float* __restrict__ w_h1, const float* __restrict__ b_h1,
    const float* __restrict__ w_out, const float* __restrict__ b_out,
    float* __restrict__ out, int npts)
{
    __shared__ half_t actS[4][2][32 * 64];

    const int t    = threadIdx.x;
    const int lane = t & 63;
    const int wv   = t >> 6;
    const int m    = lane & 15;
    const int quad = lane >> 4;

    auto loadA = [&](const float* __restrict__ W, int ncol, int row, int col) -> half8 {
        const float* p = W + row * ncol + col;
        const float4v lo = *reinterpret_cast<const float4v*>(p);
        const float4v hi = *reinterpret_cast<const float4v*>(p + 4);
        half8 r;
        r[0] = (half_t)lo[0]; r[1] = (half_t)lo[1]; r[2] = (half_t)lo[2]; r[3] = (half_t)lo[3];
        r[4] = (half_t)hi[0]; r[5] = (half_t)hi[1]; r[6] = (half_t)hi[2]; r[7] = (half_t)hi[3];
        return r;
    };

    half8 aL1[4], aL2[8], aL3[8], aL4[2];
    #pragma unroll
    for (int mt = 0; mt < 4; ++mt) aL1[mt] = loadA(w_in, 32, mt * 16 + m, quad * 8);
    #pragma unroll
    for (int mt = 0; mt < 4; ++mt) {
        aL2[mt * 2 + 0] = loadA(w_h0, 64, mt * 16 + m, 0 * 32 + quad * 8);
        aL2[mt * 2 + 1] = loadA(w_h0, 64, mt * 16 + m, 1 * 32 + quad * 8);
        aL3[mt * 2 + 0] = loadA(w_h1, 64, mt * 16 + m, 0 * 32 + quad * 8);
        aL3[mt * 2 + 1] = loadA(w_h1, 64, mt * 16 + m, 1 * 32 + quad * 8);
    }
    aL4[0] = loadA(w_out, 64, m, 0 * 32 + quad * 8);
    aL4[1] = loadA(w_out, 64, m, 1 * 32 + quad * 8);

    float4v bL1[4], bL2[4], bL3[4], bL4;
    #pragma unroll
    for (int mt = 0; mt < 4; ++mt) {
        bL1[mt] = *reinterpret_cast<const float4v*>(b_in + mt * 16 + quad * 4);
        bL2[mt] = *reinterpret_cast<const float4v*>(b_h0 + mt * 16 + quad * 4);
        bL3[mt] = *reinterpret_cast<const float4v*>(b_h1 + mt * 16 + quad * 4);
    }
    bL4 = *reinterpret_cast<const float4v*>(b_out + quad * 4);

    half_t* const ping = &actS[wv][0][0];
    half_t* const pong = &actS[wv][1][0];
    const float4v zero = {0.f, 0.f, 0.f, 0.f};

    auto storeTile = [&](half_t* buf, int lp, int mt, float4v acc, float4v bias) {
        half4 h4;
        #pragma unroll
        for (int r = 0; r < 4; ++r)
            h4[r] = (half_t)fmaxf(fmaf(bias[r], SCALE, acc[r]), 0.f);
        const int c16  = mt * 2 + (quad >> 1);
        const int phys = c16 ^ (lp & 7);
        *reinterpret_cast<half4*>(&buf[lp * 64 + phys * 8 + (quad & 1) * 4]) = h4;
    };
    auto loadB = [&](const half_t* buf, int lp, int h) -> half8 {
        const int phys = (h * 4 + quad) ^ (lp & 7);
        return *reinterpret_cast<const half8*>(&buf[lp * 64 + phys * 8]);
    };

    for (int g = 0; g < 2; ++g) {
        #pragma unroll
        for (int nt = 0; nt < 2; ++nt) {
            const int lp  = nt * 16 + m;
            const size_t ptg = (size_t)blockIdx.x * 256 + (size_t)wv * 64 + g * 32 + lp;

            // ---- layer 1: B-frag from transposed enc: k = quad*8 + j -> level quad*4+d ----
            half8 be;
            #pragma unroll
            for (int d = 0; d < 4; ++d) {
                const int L = quad * 4 + d;
                const half2v v = *reinterpret_cast<const half2v*>(&encT[((size_t)L * npts + ptg) * 2]);
                be[d * 2 + 0] = v[0];
                be[d * 2 + 1] = v[1];
            }
            #pragma unroll
            for (int mt = 0; mt < 4; ++mt) {
                float4v acc = mfma16(aL1[mt], be, zero);
                storeTile(ping, lp, mt, acc, bL1[mt]);
            }

            // ---- layer 2 ----
            {
                const half8 p0 = loadB(ping, lp, 0);
                const half8 p1 = loadB(ping, lp, 1);
                #pragma unroll
                for (int mt = 0; mt < 4; ++mt) {
                    float4v acc = mfma16(aL2[mt * 2 + 0], p0, zero);
                    acc         = mfma16(aL2[mt * 2 + 1], p1, acc);
                    storeTile(pong, lp, mt, acc, bL2[mt]);
                }
            }

            // ---- layer 3 ----
            {
                const half8 p0 = loadB(pong, lp, 0);
                const half8 p1 = loadB(pong, lp, 1);
                #pragma unroll
                for (int mt = 0; mt < 4; ++mt) {
                    float4v acc = mfma16(aL3[mt * 2 + 0], p0, zero);
                    acc         = mfma16(aL3[mt * 2 + 1], p1, acc);
                    storeTile(ping, lp, mt, acc, bL3[mt]);
                }
            }

            // ---- layer 4 ----
            {
                const half8 p0 = loadB(ping, lp, 0);
                const half8 p1 = loadB(ping, lp, 1);
                float4v acc = mfma16(aL4[0], p0, zero);
                acc         = mfma16(aL4[1], p1, acc);
                float4v res;
                #pragma unroll
                for (int r = 0; r < 4; ++r)
                    res[r] = fmaf(acc[r], INV_SCALE, bL4[r]);
                *reinterpret_cast<float4v*>(out + ptg * 16 + quad * 4) = res;
            }
        }
    }
}

// ---------------- Fallback: R4 fused kernel (used only if ws too small) ----------------
__global__ __launch_bounds__(256, 2) void nerf_fused(
    const float* __restrict__ coords,
    const float2* __restrict__ tab,
    const float* __restrict__ w_in, const float* __restrict__ b_in,
    const float* __restrict__ w_h0, const float* __restrict__ b_h0,
    const float* __restrict__ w_h1, const float* __restrict__ b_h1,
    const float* __restrict__ w_out, const float* __restrict__ b_out,
    float* __restrict__ out, int npts)
{
    __shared__ half_t encS[256 * 40];
    __shared__ half_t actS[4][2][32 * 64];

    const int t    = threadIdx.x;
    const int lane = t & 63;
    const int wv   = t >> 6;
    const int m    = lane & 15;
    const int quad = lane >> 4;
    const int pt = blockIdx.x * 256 + t;

    {
        const float cx = coords[pt * 3 + 0];
        const float cy = coords[pt * 3 + 1];
        const float cz = coords[pt * 3 + 2];
        float enc[32];
        #pragma unroll
        for (int l = 0; l < NLVL; ++l) {
            const float r = RES_C[l];
            const float sx = cx * r, sy = cy * r, sz = cz * r;
            const float fx = floorf(sx), fy = floorf(sy), fz = floorf(sz);
            const float gx = ceilf(sx),  gy = ceilf(sy),  gz = ceilf(sz);
            const unsigned hfx = (unsigned)(int)fx;
            const unsigned hgx = (unsigned)(int)gx;
            const unsigned hfy = (unsigned)(int)fy * 2654435761u;
            const unsigned hgy = (unsigned)(int)gy * 2654435761u;
            const unsigned hfz = (unsigned)(int)fz * 805459861u;
            const unsigned hgz = (unsigned)(int)gz * 805459861u;
            const float tx = sx - fx, ty = sy - fy, tz = sz - fz;
            const float ux = gx - sx, uy = gy - sy, uz = gz - sz;
            const unsigned lbase = ((unsigned)l) << LOGT;
            float e0 = 0.f, e1 = 0.f;
            #pragma unroll
            for (int o = 0; o < 8; ++o) {
                const unsigned h = ((o & 4) ? hgx : hfx)
                                 ^ ((o & 2) ? hgy : hfy)
                                 ^ ((o & 1) ? hgz : hfz);
                const unsigned idx = h & TMASK;
                const float w = (((o & 4) ? tx : ux)
                              *  ((o & 2) ? ty : uy))
                              *  ((o & 1) ? tz : uz);
                const float2 fv = tab[lbase + idx];
                e0 = fmaf(w, fv.x, e0);
                e1 = fmaf(w, fv.y, e1);
            }
            enc[2 * l + 0] = e0;
            enc[2 * l + 1] = e1;
        }
        #pragma unroll
        for (int c = 0; c < 4; ++c) {
            half8 h8;
            #pragma unroll
            for (int j = 0; j < 8; ++j) h8[j] = (half_t)(enc[c * 8 + j] * SCALE);
            *reinterpret_cast<half8*>(&encS[t * 40 + c * 8]) = h8;
        }
    }

    auto loadA = [&](const float* __restrict__ W, int ncol, int row, int col) -> half8 {
        const float* p = W + row * ncol + col;
        const float4v lo = *reinterpret_cast<const float4v*>(p);
        const float4v hi = *reinterpret_cast<const float4v*>(p + 4);
        half8 r;
        r[0] = (half_t)lo[0]; r[1] = (half_t)lo[1]; r[2] = (half_t)lo[2]; r[3] = (half_t)lo[3];
        r[4] = (half_t)hi[0]; r[5] = (half_t)hi[1]; r[6] = (half_t)hi[2]; r[7] = (half_t)hi[3];
        return r;
    };

    half8 aL1[4], aL2[8], aL3[8], aL4[2];
    #pragma unroll
    for (int mt = 0; mt < 4; ++mt) aL1[mt] = loadA(w_in, 32, mt * 16 + m, quad * 8);
    #pragma unroll
    for (int mt = 0; mt < 4; ++mt) {
        aL2[mt * 2 + 0] = loadA(w_h0, 64, mt * 16 + m, 0 * 32 + quad * 8);
        aL2[mt * 2 + 1] = loadA(w_h0, 64, mt * 16 + m, 1 * 32 + quad * 8);
        aL3[mt * 2 + 0] = loadA(w_h1, 64, mt * 16 + m, 0 * 32 + quad * 8);
        aL3[mt * 2 + 1] = loadA(w_h1, 64, mt * 16 + m, 1 * 32 + quad * 8);
    }
    aL4[0] = loadA(w_out, 64, m, 0 * 32 + quad * 8);
    aL4[1] = loadA(w_out, 64, m, 1 * 32 + quad * 8);

    float4v bL1[4], bL2[4], bL3[4], bL4;
    #pragma unroll
    for (int mt = 0; mt < 4; ++mt) {
        bL1[mt] = *reinterpret_cast<const float4v*>(b_in + mt * 16 + quad * 4);
        bL2[mt] = *reinterpret_cast<const float4v*>(b_h0 + mt * 16 + quad * 4);
        bL3[mt] = *reinterpret_cast<const float4v*>(b_h1 + mt * 16 + quad * 4);
    }
    bL4 = *reinterpret_cast<const float4v*>(b_out + quad * 4);

    half_t* const ping = &actS[wv][0][0];
    half_t* const pong = &actS[wv][1][0];
    const float4v zero = {0.f, 0.f, 0.f, 0.f};

    auto storeTile = [&](half_t* buf, int lp, int mt, float4v acc, float4v bias) {
        half4 h4;
        #pragma unroll
        for (int r = 0; r < 4; ++r)
            h4[r] = (half_t)fmaxf(fmaf(bias[r], SCALE, acc[r]), 0.f);
        const int c16  = mt * 2 + (quad >> 1);
        const int phys = c16 ^ (lp & 7);
        *reinterpret_cast<half4*>(&buf[lp * 64 + phys * 8 + (quad & 1) * 4]) = h4;
    };
    auto loadB = [&](const half_t* buf, int lp, int h) -> half8 {
        const int phys = (h * 4 + quad) ^ (lp & 7);
        return *reinterpret_cast<const half8*>(&buf[lp * 64 + phys * 8]);
    };

    for (int g = 0; g < 2; ++g) {
        #pragma unroll
        for (int nt = 0; nt < 2; ++nt) {
            const int lp   = nt * 16 + m;
            const int prow = wv * 64 + g * 32 + lp;
            const half8 be = *reinterpret_cast<const half8*>(&encS[prow * 40 + quad * 8]);
            #pragma unroll
            for (int mt = 0; mt < 4; ++mt) {
                float4v acc = mfma16(aL1[mt], be, zero);
                storeTile(ping, lp, mt, acc, bL1[mt]);
            }
            {
                const half8 p0 = loadB(ping, lp, 0);
                const half8 p1 = loadB(ping, lp, 1);
                #pragma unroll
                for (int mt = 0; mt < 4; ++mt) {
                    float4v acc = mfma16(aL2[mt * 2 + 0], p0, zero);
                    acc         = mfma16(aL2[mt * 2 + 1], p1, acc);
                    storeTile(pong, lp, mt, acc, bL2[mt]);
                }
            }
            {
                const half8 p0 = loadB(pong, lp, 0);
                const half8 p1 = loadB(pong, lp, 1);
                #pragma unroll
                for (int mt = 0; mt < 4; ++mt) {
                    float4v acc = mfma16(aL3[mt * 2 + 0], p0, zero);
                    acc         = mfma16(aL3[mt * 2 + 1], p1, acc);
                    storeTile(ping, lp, mt, acc, bL3[mt]);
                }
            }
            {
                const half8 p0 = loadB(ping, lp, 0);
                const half8 p1 = loadB(ping, lp, 1);
                float4v acc = mfma16(aL4[0], p0, zero);
                acc         = mfma16(aL4[1], p1, acc);
                float4v res;
                #pragma unroll
                for (int r = 0; r < 4; ++r)
                    res[r] = fmaf(acc[r], INV_SCALE, bL4[r]);
                const size_t ptg = (size_t)blockIdx.x * 256 + (size_t)wv * 64 + g * 32 + lp;
                *reinterpret_cast<float4v*>(out + ptg * 16 + quad * 4) = res;
            }
        }
    }
}

extern "C" void kernel_launch(void* const* d_in, const int* in_sizes, int n_in,
                              void* d_out, int out_size, void* d_ws, size_t ws_size,
                              hipStream_t stream) {
    const float*  coords = (const float*)d_in[0];
    const float2* tables = (const float2*)d_in[1];
    const float*  w_in   = (const float*)d_in[2];
    const float*  b_in   = (const float*)d_in[3];
    const float*  w_h0   = (const float*)d_in[4];
    const float*  b_h0   = (const float*)d_in[5];
    const float*  w_h1   = (const float*)d_in[6];
    const float*  b_h1   = (const float*)d_in[7];
    const float*  w_out  = (const float*)d_in[8];
    const float*  b_out  = (const float*)d_in[9];
    float* out = (float*)d_out;

    const int npts = in_sizes[0] / 3;      // 262144
    const size_t encBytes = (size_t)npts * 32 * sizeof(half_t);  // 16.8 MB

    if (ws_size >= encBytes && (npts & 255) == 0) {
        half_t* encT = (half_t*)d_ws;
        const int bpl = npts >> 8;                 // blocks per level
        nerf_encode_lvl<<<bpl * NLVL, 256, 0, stream>>>(coords, tables, encT, npts);
        nerf_mlp<<<npts / 256, 256, 0, stream>>>(encT,
                                                 w_in, b_in, w_h0, b_h0,
                                                 w_h1, b_h1, w_out, b_out,
                                                 out, npts);
    } else {
        nerf_fused<<<npts / 256, 256, 0, stream>>>(coords, tables,
                                                   w_in, b_in, w_h0, b_h0,
                                                   w_h1, b_h1, w_out, b_out,
                                                   out, npts);
    }
}

// Round 7
// 220.137 us; speedup vs baseline: 1.7248x; 1.1866x over previous
//
#include <hip/hip_runtime.h>

#define NLVL 16
#define LOGT 19
#define TMASK ((1u << LOGT) - 1u)
#define SCALE 4096.0f
#define INV_SCALE (1.0f / 4096.0f)

typedef _Float16 half_t;
typedef half_t half8 __attribute__((ext_vector_type(8)));
typedef half_t half4 __attribute__((ext_vector_type(4)));
typedef half_t half2v __attribute__((ext_vector_type(2)));
typedef float  float4v __attribute__((ext_vector_type(4)));

__device__ __constant__ float RES_C[NLVL] = {16.f, 20.f, 25.f, 32.f, 40.f, 50.f, 64.f, 80.f,
                                             101.f, 128.f, 161.f, 203.f, 256.f, 322.f, 406.f, 512.f};

__device__ __forceinline__ float4v mfma16(half8 a, half8 b, float4v c) {
    return __builtin_amdgcn_mfma_f32_16x16x32_f16(a, b, c, 0, 0, 0);
}

// ---------------- Kernel A: level-major encode, 2 lanes per (point, level) ----------------
// Even lane handles the floor-x corners, odd lane the ceil-x corners (4 y/z corners each).
// Because the x hash coefficient is 1, the lane-pair's 4 gather addresses land in the same
// 64B line 87.5% of the time -> TA coalesces them into one L2 request (8 -> ~4.5 req/pt-lvl).
// Level is the slow grid dimension (one ~4MB table L2-resident per XCD at a time).
__global__ __launch_bounds__(256, 8) void nerf_encode_pair(
    const float* __restrict__ coords,
    const float2* __restrict__ tab,
    half_t* __restrict__ encT, int npts)
{
    const int bpl = npts >> 7;                    // blocks per level (128 points per block)
    const int l    = blockIdx.x / bpl;
    const int side = threadIdx.x & 1;             // 0 = floor-x, 1 = ceil-x
    const int p    = (blockIdx.x % bpl) * 128 + (threadIdx.x >> 1);

    const float cx = coords[p * 3 + 0];
    const float cy = coords[p * 3 + 1];
    const float cz = coords[p * 3 + 2];

    const float r = RES_C[l];
    const float sx = cx * r, sy = cy * r, sz = cz * r;
    const float fx = floorf(sx), fy = floorf(sy), fz = floorf(sz);
    const float gx = ceilf(sx),  gy = ceilf(sy),  gz = ceilf(sz);

    // this lane's x-side hash and weight factor:
    //   x = ceil  -> weight factor (sx - fx) ; x = floor -> (gx - sx)
    const unsigned hx = side ? (unsigned)(int)gx : (unsigned)(int)fx;
    const float    wx = side ? (sx - fx) : (gx - sx);

    const unsigned hfy = (unsigned)(int)fy * 2654435761u;
    const unsigned hgy = (unsigned)(int)gy * 2654435761u;
    const unsigned hfz = (unsigned)(int)fz * 805459861u;
    const unsigned hgz = (unsigned)(int)gz * 805459861u;

    const float ty = sy - fy, tz = sz - fz;
    const float uy = gy - sy, uz = gz - sz;

    const float2* __restrict__ base = tab + (((unsigned)l) << LOGT);

    // 4 y/z corners for this x-side, issued as one independent batch
    const unsigned i0 = (hx ^ hfy ^ hfz) & TMASK;  const float w0 = wx * uy * uz;
    const unsigned i1 = (hx ^ hfy ^ hgz) & TMASK;  const float w1 = wx * uy * tz;
    const unsigned i2 = (hx ^ hgy ^ hfz) & TMASK;  const float w2 = wx * ty * uz;
    const unsigned i3 = (hx ^ hgy ^ hgz) & TMASK;  const float w3 = wx * ty * tz;

    const float2 v0 = base[i0];
    const float2 v1 = base[i1];
    const float2 v2 = base[i2];
    const float2 v3 = base[i3];

    float e0 = w0 * v0.x + w1 * v1.x + w2 * v2.x + w3 * v3.x;
    float e1 = w0 * v0.y + w1 * v1.y + w2 * v2.y + w3 * v3.y;

    // combine the two x-sides (same wave, adjacent lanes)
    e0 += __shfl_xor(e0, 1, 64);
    e1 += __shfl_xor(e1, 1, 64);

    if (side == 0) {
        half2v hv;
        hv[0] = (half_t)(e0 * SCALE);
        hv[1] = (half_t)(e1 * SCALE);
        *reinterpret_cast<half2v*>(&encT[((size_t)l * npts + p) * 2]) = hv;
    }
}

// ---------------- Kernel B: MFMA MLP (enc from transposed global buffer) ----------------
__global__ __launch_bounds__(256, 2) void nerf_mlp(
    const half_t* __restrict__ encT,
    const float* __restrict__ w_in, const float* __restrict__ b_in,
    const float* __restrict__ w_h0, const float* __restrict__ b_h0,
    const float* __restrict__ w_h1, const float* __restrict__ b_h1,
    const float* __restrict__ w_out, const float* __restrict__ b_out,
    float* __restrict__ out, int npts)
{
    __shared__ half_t actS[4][2][32 * 64];

    const int t    = threadIdx.x;
    const int lane = t & 63;
    const int wv   = t >> 6;
    const int m    = lane & 15;
    const int quad = lane >> 4;

    auto loadA = [&](const float* __restrict__ W, int ncol, int row, int col) -> half8 {
        const float* p = W + row * ncol + col;
        const float4v lo = *reinterpret_cast<const float4v*>(p);
        const float4v hi = *reinterpret_cast<const float4v*>(p + 4);
        half8 r;
        r[0] = (half_t)lo[0]; r[1] = (half_t)lo[1]; r[2] = (half_t)lo[2]; r[3] = (half_t)lo[3];
        r[4] = (half_t)hi[0]; r[5] = (half_t)hi[1]; r[6] = (half_t)hi[2]; r[7] = (half_t)hi[3];
        return r;
    };

    half8 aL1[4], aL2[8], aL3[8], aL4[2];
    #pragma unroll
    for (int mt = 0; mt < 4; ++mt) aL1[mt] = loadA(w_in, 32, mt * 16 + m, quad * 8);
    #pragma unroll
    for (int mt = 0; mt < 4; ++mt) {
        aL2[mt * 2 + 0] = loadA(w_h0, 64, mt * 16 + m, 0 * 32 + quad * 8);
        aL2[mt * 2 + 1] = loadA(w_h0, 64, mt * 16 + m, 1 * 32 + quad * 8);
        aL3[mt * 2 + 0] = loadA(w_h1, 64, mt * 16 + m, 0 * 32 + quad * 8);
        aL3[mt * 2 + 1] = loadA(w_h1, 64, mt * 16 + m, 1 * 32 + quad * 8);
    }
    aL4[0] = loadA(w_out, 64, m, 0 * 32 + quad * 8);
    aL4[1] = loadA(w_out, 64, m, 1 * 32 + quad * 8);

    float4v bL1[4], bL2[4], bL3[4], bL4;
    #pragma unroll
    for (int mt = 0; mt < 4; ++mt) {
        bL1[mt] = *reinterpret_cast<const float4v*>(b_in + mt * 16 + quad * 4);
        bL2[mt] = *reinterpret_cast<const float4v*>(b_h0 + mt * 16 + quad * 4);
        bL3[mt] = *reinterpret_cast<const float4v*>(b_h1 + mt * 16 + quad * 4);
    }
    bL4 = *reinterpret_cast<const float4v*>(b_out + quad * 4);

    half_t* const ping = &actS[wv][0][0];
    half_t* const pong = &actS[wv][1][0];
    const float4v zero = {0.f, 0.f, 0.f, 0.f};

    auto storeTile = [&](half_t* buf, int lp, int mt, float4v acc, float4v bias) {
        half4 h4;
        #pragma unroll
        for (int r = 0; r < 4; ++r)
            h4[r] = (half_t)fmaxf(fmaf(bias[r], SCALE, acc[r]), 0.f);
        const int c16  = mt * 2 + (quad >> 1);
        const int phys = c16 ^ (lp & 7);
        *reinterpret_cast<half4*>(&buf[lp * 64 + phys * 8 + (quad & 1) * 4]) = h4;
    };
    auto loadB = [&](const half_t* buf, int lp, int h) -> half8 {
        const int phys = (h * 4 + quad) ^ (lp & 7);
        return *reinterpret_cast<const half8*>(&buf[lp * 64 + phys * 8]);
    };

    for (int g = 0; g < 2; ++g) {
        #pragma unroll
        for (int nt = 0; nt < 2; ++nt) {
            const int lp  = nt * 16 + m;
            const size_t ptg = (size_t)blockIdx.x * 256 + (size_t)wv * 64 + g * 32 + lp;

            // ---- layer 1: B-frag from transposed enc: k = quad*8 + j -> level quad*4+d ----
            half8 be;
            #pragma unroll
            for (int d = 0; d < 4; ++d) {
                const int L = quad * 4 + d;
                const half2v v = *reinterpret_cast<const half2v*>(&encT[((size_t)L * npts + ptg) * 2]);
                be[d * 2 + 0] = v[0];
                be[d * 2 + 1] = v[1];
            }
            #pragma unroll
            for (int mt = 0; mt < 4; ++mt) {
                float4v acc = mfma16(aL1[mt], be, zero);
                storeTile(ping, lp, mt, acc, bL1[mt]);
            }

            // ---- layer 2 ----
            {
                const half8 p0 = loadB(ping, lp, 0);
                const half8 p1 = loadB(ping, lp, 1);
                #pragma unroll
                for (int mt = 0; mt < 4; ++mt) {
                    float4v acc = mfma16(aL2[mt * 2 + 0], p0, zero);
                    acc         = mfma16(aL2[mt * 2 + 1], p1, acc);
                    storeTile(pong, lp, mt, acc, bL2[mt]);
                }
            }

            // ---- layer 3 ----
            {
                const half8 p0 = loadB(pong, lp, 0);
                const half8 p1 = loadB(pong, lp, 1);
                #pragma unroll
                for (int mt = 0; mt < 4; ++mt) {
                    float4v acc = mfma16(aL3[mt * 2 + 0], p0, zero);
                    acc         = mfma16(aL3[mt * 2 + 1], p1, acc);
                    storeTile(ping, lp, mt, acc, bL3[mt]);
                }
            }

            // ---- layer 4 ----
            {
                const half8 p0 = loadB(ping, lp, 0);
                const half8 p1 = loadB(ping, lp, 1);
                float4v acc = mfma16(aL4[0], p0, zero);
                acc         = mfma16(aL4[1], p1, acc);
                float4v res;
                #pragma unroll
                for (int r = 0; r < 4; ++r)
                    res[r] = fmaf(acc[r], INV_SCALE, bL4[r]);
                *reinterpret_cast<float4v*>(out + ptg * 16 + quad * 4) = res;
            }
        }
    }
}

// ---------------- Fallback: R4 fused kernel (used only if ws too small) ----------------
__global__ __launch_bounds__(256, 2) void nerf_fused(
    const float* __restrict__ coords,
    const float2* __restrict__ tab,
    const float* __restrict__ w_in, const float* __restrict__ b_in,
    const float* __restrict__ w_h0, const float* __restrict__ b_h0,
    const float* __restrict__ w_h1, const float* __restrict__ b_h1,
    const float* __restrict__ w_out, const float* __restrict__ b_out,
    float* __restrict__ out, int npts)
{
    __shared__ half_t encS[256 * 40];
    __shared__ half_t actS[4][2][32 * 64];

    const int t    = threadIdx.x;
    const int lane = t & 63;
    const int wv   = t >> 6;
    const int m    = lane & 15;
    const int quad = lane >> 4;
    const int pt = blockIdx.x * 256 + t;

    {
        const float cx = coords[pt * 3 + 0];
        const float cy = coords[pt * 3 + 1];
        const float cz = coords[pt * 3 + 2];
        float enc[32];
        #pragma unroll
        for (int l = 0; l < NLVL; ++l) {
            const float r = RES_C[l];
            const float sx = cx * r, sy = cy * r, sz = cz * r;
            const float fx = floorf(sx), fy = floorf(sy), fz = floorf(sz);
            const float gx = ceilf(sx),  gy = ceilf(sy),  gz = ceilf(sz);
            const unsigned hfx = (unsigned)(int)fx;
            const unsigned hgx = (unsigned)(int)gx;
            const unsigned hfy = (unsigned)(int)fy * 2654435761u;
            const unsigned hgy = (unsigned)(int)gy * 2654435761u;
            const unsigned hfz = (unsigned)(int)fz * 805459861u;
            const unsigned hgz = (unsigned)(int)gz * 805459861u;
            const float tx = sx - fx, ty = sy - fy, tz = sz - fz;
            const float ux = gx - sx, uy = gy - sy, uz = gz - sz;
            const unsigned lbase = ((unsigned)l) << LOGT;
            float e0 = 0.f, e1 = 0.f;
            #pragma unroll
            for (int o = 0; o < 8; ++o) {
                const unsigned h = ((o & 4) ? hgx : hfx)
                                 ^ ((o & 2) ? hgy : hfy)
                                 ^ ((o & 1) ? hgz : hfz);
                const unsigned idx = h & TMASK;
                const float w = (((o & 4) ? tx : ux)
                              *  ((o & 2) ? ty : uy))
                              *  ((o & 1) ? tz : uz);
                const float2 fv = tab[lbase + idx];
                e0 = fmaf(w, fv.x, e0);
                e1 = fmaf(w, fv.y, e1);
            }
            enc[2 * l + 0] = e0;
            enc[2 * l + 1] = e1;
        }
        #pragma unroll
        for (int c = 0; c < 4; ++c) {
            half8 h8;
            #pragma unroll
            for (int j = 0; j < 8; ++j) h8[j] = (half_t)(enc[c * 8 + j] * SCALE);
            *reinterpret_cast<half8*>(&encS[t * 40 + c * 8]) = h8;
        }
    }

    auto loadA = [&](const float* __restrict__ W, int ncol, int row, int col) -> half8 {
        const float* p = W + row * ncol + col;
        const float4v lo = *reinterpret_cast<const float4v*>(p);
        const float4v hi = *reinterpret_cast<const float4v*>(p + 4);
        half8 r;
        r[0] = (half_t)lo[0]; r[1] = (half_t)lo[1]; r[2] = (half_t)lo[2]; r[3] = (half_t)lo[3];
        r[4] = (half_t)hi[0]; r[5] = (half_t)hi[1]; r[6] = (half_t)hi[2]; r[7] = (half_t)hi[3];
        return r;
    };

    half8 aL1[4], aL2[8], aL3[8], aL4[2];
    #pragma unroll
    for (int mt = 0; mt < 4; ++mt) aL1[mt] = loadA(w_in, 32, mt * 16 + m, quad * 8);
    #pragma unroll
    for (int mt = 0; mt < 4; ++mt) {
        aL2[mt * 2 + 0] = loadA(w_h0, 64, mt * 16 + m, 0 * 32 + quad * 8);
        aL2[mt * 2 + 1] = loadA(w_h0, 64, mt * 16 + m, 1 * 32 + quad * 8);
        aL3[mt * 2 + 0] = loadA(w_h1, 64, mt * 16 + m, 0 * 32 + quad * 8);
        aL3[mt * 2 + 1] = loadA(w_h1, 64, mt * 16 + m, 1 * 32 + quad * 8);
    }
    aL4[0] = loadA(w_out, 64, m, 0 * 32 + quad * 8);
    aL4[1] = loadA(w_out, 64, m, 1 * 32 + quad * 8);

    float4v bL1[4], bL2[4], bL3[4], bL4;
    #pragma unroll
    for (int mt = 0; mt < 4; ++mt) {
        bL1[mt] = *reinterpret_cast<const float4v*>(b_in + mt * 16 + quad * 4);
        bL2[mt] = *reinterpret_cast<const float4v*>(b_h0 + mt * 16 + quad * 4);
        bL3[mt] = *reinterpret_cast<const float4v*>(b_h1 + mt * 16 + quad * 4);
    }
    bL4 = *reinterpret_cast<const float4v*>(b_out + quad * 4);

    half_t* const ping = &actS[wv][0][0];
    half_t* const pong = &actS[wv][1][0];
    const float4v zero = {0.f, 0.f, 0.f, 0.f};

    auto storeTile = [&](half_t* buf, int lp, int mt, float4v acc, float4v bias) {
        half4 h4;
        #pragma unroll
        for (int r = 0; r < 4; ++r)
            h4[r] = (half_t)fmaxf(fmaf(bias[r], SCALE, acc[r]), 0.f);
        const int c16  = mt * 2 + (quad >> 1);
        const int phys = c16 ^ (lp & 7);
        *reinterpret_cast<half4*>(&buf[lp * 64 + phys * 8 + (quad & 1) * 4]) = h4;
    };
    auto loadB = [&](const half_t* buf, int lp, int h) -> half8 {
        const int phys = (h * 4 + quad) ^ (lp & 7);
        return *reinterpret_cast<const half8*>(&buf[lp * 64 + phys * 8]);
    };

    for (int g = 0; g < 2; ++g) {
        #pragma unroll
        for (int nt = 0; nt < 2; ++nt) {
            const int lp   = nt * 16 + m;
            const int prow = wv * 64 + g * 32 + lp;
            const half8 be = *reinterpret_cast<const half8*>(&encS[prow * 40 + quad * 8]);
            #pragma unroll
            for (int mt = 0; mt < 4; ++mt) {
                float4v acc = mfma16(aL1[mt], be, zero);
                storeTile(ping, lp, mt, acc, bL1[mt]);
            }
            {
                const half8 p0 = loadB(ping, lp, 0);
                const half8 p1 = loadB(ping, lp, 1);
                #pragma unroll
                for (int mt = 0; mt < 4; ++mt) {
                    float4v acc = mfma16(aL2[mt * 2 + 0], p0, zero);
                    acc         = mfma16(aL2[mt * 2 + 1], p1, acc);
                    storeTile(pong, lp, mt, acc, bL2[mt]);
                }
            }
            {
                const half8 p0 = loadB(pong, lp, 0);
                const half8 p1 = loadB(pong, lp, 1);
                #pragma unroll
                for (int mt = 0; mt < 4; ++mt) {
                    float4v acc = mfma16(aL3[mt * 2 + 0], p0, zero);
                    acc         = mfma16(aL3[mt * 2 + 1], p1, acc);
                    storeTile(ping, lp, mt, acc, bL3[mt]);
                }
            }
            {
                const half8 p0 = loadB(ping, lp, 0);
                const half8 p1 = loadB(ping, lp, 1);
                float4v acc = mfma16(aL4[0], p0, zero);
                acc         = mfma16(aL4[1], p1, acc);
                float4v res;
                #pragma unroll
                for (int r = 0; r < 4; ++r)
                    res[r] = fmaf(acc[r], INV_SCALE, bL4[r]);
                const size_t ptg = (size_t)blockIdx.x * 256 + (size_t)wv * 64 + g * 32 + lp;
                *reinterpret_cast<float4v*>(out + ptg * 16 + quad * 4) = res;
            }
        }
    }
}

extern "C" void kernel_launch(void* const* d_in, const int* in_sizes, int n_in,
                              void* d_out, int out_size, void* d_ws, size_t ws_size,
                              hipStream_t stream) {
    const float*  coords = (const float*)d_in[0];
    const float2* tables = (const float2*)d_in[1];
    const float*  w_in   = (const float*)d_in[2];
    const float*  b_in   = (const float*)d_in[3];
    const float*  w_h0   = (const float*)d_in[4];
    const float*  b_h0   = (const float*)d_in[5];
    const float*  w_h1   = (const float*)d_in[6];
    const float*  b_h1   = (const float*)d_in[7];
    const float*  w_out  = (const float*)d_in[8];
    const float*  b_out  = (const float*)d_in[9];
    float* out = (float*)d_out;

    const int npts = in_sizes[0] / 3;      // 262144
    const size_t encBytes = (size_t)npts * 32 * sizeof(half_t);  // 16.8 MB

    if (ws_size >= encBytes && (npts & 255) == 0) {
        half_t* encT = (half_t*)d_ws;
        const int bpl = npts >> 7;                 // blocks per level (128 pts/block, 2 lanes/pt)
        nerf_encode_pair<<<bpl * NLVL, 256, 0, stream>>>(coords, tables, encT, npts);
        nerf_mlp<<<npts / 256, 256, 0, stream>>>(encT,
                                                 w_in, b_in, w_h0, b_h0,
                                                 w_h1, b_h1, w_out, b_out,
                                                 out, npts);
    } else {
        nerf_fused<<<npts / 256, 256, 0, stream>>>(coords, tables,
                                                   w_in, b_in, w_h0, b_h0,
                                                   w_h1, b_h1, w_out, b_out,
                                                   out, npts);
    }
}